// Round 1
// baseline (636.343 us; speedup 1.0000x reference)
//
#include <hip/hip_runtime.h>
#include <math.h>

#define NN 50000
#define NE 800000
#define FIN 500
#define DH 128
#define D2H 256
#define NCLS 40
#define NB 196  // scan blocks = ceil(NN/256)

typedef short short8 __attribute__((ext_vector_type(8)));
typedef float f32x4 __attribute__((ext_vector_type(4)));

__device__ __forceinline__ unsigned short f2bf(float f) {
    unsigned u = __float_as_uint(f);
    unsigned r = (u + 0x7FFFu + ((u >> 16) & 1u)) >> 16;
    return (unsigned short)r;
}
__device__ __forceinline__ float bf2f(unsigned short h) {
    return __uint_as_float(((unsigned)h) << 16);
}

// ---- weight split+transpose: W[Ksrc][N] fp32 -> dst [N][2*Kpad] bf16 (hi plane | lo plane) ----
__global__ void k_wsplit(const float* __restrict__ W, short* __restrict__ dst,
                         int Ksrc, int N, int Kpad, int koff, int llog) {
    int i = blockIdx.x * 256 + threadIdx.x;
    int len = 1 << llog;
    if (i >= N * len) return;
    int n = i >> llog, kk = i & (len - 1);
    float v = (kk < Ksrc) ? W[(size_t)kk * N + n] : 0.f;
    unsigned short hi = f2bf(v);
    float lo = v - bf2f(hi);
    size_t di = (size_t)n * (2 * Kpad) + koff + kk;
    dst[di] = (short)hi;
    dst[di + Kpad] = (short)f2bf(lo);
}

// ---------------- counting sort of edges by dst ----------------
__global__ void k_count(const int* __restrict__ dst, int* __restrict__ deg) {
    int e = blockIdx.x * blockDim.x + threadIdx.x;
    if (e < NE) atomicAdd(&deg[dst[e]], 1);
}

__global__ void k_scan1(const int* __restrict__ deg, int* __restrict__ offs,
                        int* __restrict__ bsum) {
    __shared__ int sm[256];
    int tid = threadIdx.x;
    int i = blockIdx.x * 256 + tid;
    int v = (i < NN) ? deg[i] : 0;
    sm[tid] = v;
    __syncthreads();
    for (int off = 1; off < 256; off <<= 1) {
        int t = (tid >= off) ? sm[tid - off] : 0;
        __syncthreads();
        sm[tid] += t;
        __syncthreads();
    }
    if (i < NN) offs[i] = sm[tid] - v;
    if (tid == 255) bsum[blockIdx.x] = sm[255];
}

__global__ void k_scan2(const int* __restrict__ bsum, int* __restrict__ bpre,
                        int* __restrict__ offs) {
    __shared__ int sm[256];
    int tid = threadIdx.x;
    int v = (tid < NB) ? bsum[tid] : 0;
    sm[tid] = v;
    __syncthreads();
    for (int off = 1; off < 256; off <<= 1) {
        int t = (tid >= off) ? sm[tid - off] : 0;
        __syncthreads();
        sm[tid] += t;
        __syncthreads();
    }
    if (tid < NB) bpre[tid] = sm[tid] - v;
    if (tid == 255) offs[NN] = sm[255];
}

__global__ void k_scan3(int* __restrict__ offs, const int* __restrict__ bpre,
                        int* __restrict__ cursor) {
    int i = blockIdx.x * 256 + threadIdx.x;
    if (i < NN) {
        int v = offs[i] + bpre[blockIdx.x];
        offs[i] = v;
        cursor[i] = v;
    }
}

__global__ void k_scatter(const int* __restrict__ src, const int* __restrict__ dst,
                          int* __restrict__ cursor, int* __restrict__ ssrc) {
    int e = blockIdx.x * blockDim.x + threadIdx.x;
    if (e < NE) {
        int p = atomicAdd(&cursor[dst[e]], 1);
        ssrc[p] = src[e];
    }
}

// ---- mean aggregation from bf16 table [NN][128] -> bf16 mean plane [NN][128] ----
__global__ __launch_bounds__(256) void k_aggb(
    const short* __restrict__ hb, const int* __restrict__ offs,
    const int* __restrict__ ssrc, short* __restrict__ mH) {
    int wid = (blockIdx.x * 256 + threadIdx.x) >> 6;
    int lane = threadIdx.x & 63;
    if (wid >= NN) return;
    int sub = lane >> 4, l16 = lane & 15;
    int beg = offs[wid], end = offs[wid + 1];
    f32x4 a0 = {0.f, 0.f, 0.f, 0.f}, a1 = {0.f, 0.f, 0.f, 0.f};
    int i = beg + sub;
    for (; i + 4 < end; i += 8) {
        int s0 = ssrc[i];
        int s1 = ssrc[i + 4];
        short8 v0 = *(const short8*)(hb + (size_t)s0 * 128 + l16 * 8);
        short8 v1 = *(const short8*)(hb + (size_t)s1 * 128 + l16 * 8);
#pragma unroll
        for (int j = 0; j < 4; ++j) {
            a0[j] += bf2f((unsigned short)v0[j]) + bf2f((unsigned short)v1[j]);
            a1[j] += bf2f((unsigned short)v0[j + 4]) + bf2f((unsigned short)v1[j + 4]);
        }
    }
    if (i < end) {
        int s0 = ssrc[i];
        short8 v0 = *(const short8*)(hb + (size_t)s0 * 128 + l16 * 8);
#pragma unroll
        for (int j = 0; j < 4; ++j) {
            a0[j] += bf2f((unsigned short)v0[j]);
            a1[j] += bf2f((unsigned short)v0[j + 4]);
        }
    }
#pragma unroll
    for (int j = 0; j < 4; ++j) {
        a0[j] += __shfl_xor(a0[j], 16);
        a0[j] += __shfl_xor(a0[j], 32);
        a1[j] += __shfl_xor(a1[j], 16);
        a1[j] += __shfl_xor(a1[j], 32);
    }
    if (sub == 0) {
        float inv = 1.f / fmaxf((float)(end - beg), 1.f);
        a0 *= inv; a1 *= inv;
        short8 hv;
#pragma unroll
        for (int j = 0; j < 4; ++j) {
            hv[j] = (short)f2bf(a0[j]);
            hv[j + 4] = (short)f2bf(a1[j]);
        }
        *(short8*)(mH + (size_t)wid * 128 + l16 * 8) = hv;
    }
}

// ---------------- barrier-free, LDS-free MFMA GEMM ----------------
// 128 threads = 2 waves; each wave owns 32 rows x BN cols (two 16-row frags).
// A fragments loaded directly global->VGPR (per-lane: row l16, k = quad*8..+7).
// B pre-split hi/lo interleaved per row: [N][2*KPAD] bf16; lo frag = hi base + KPAD imm.
// A read once from HBM (one block covers BN cols); B frags L2-resident.
// No __syncthreads anywhere -> compiler pipelines loads across k-steps freely.
template <int BN, int KPAD, int KS0, int KREAL, bool AFP32, bool RELU>
__global__ __launch_bounds__(128, 2) void k_mm2(
    const void* __restrict__ A0v, const short* __restrict__ A1,
    const short* __restrict__ Bg, const float* __restrict__ bias,
    short* __restrict__ CH, int ldc,
    float* __restrict__ F0, float* __restrict__ F1, int splitN,
    int M, int N) {
    constexpr int NT = BN / 16;
    constexpr int NS = KPAD / 32;
    constexpr int W1 = KPAD - KS0;
    int tid = threadIdx.x;
    int wave = tid >> 6, lane = tid & 63;
    int quad = lane >> 4, l16 = lane & 15;
    int rowBase = blockIdx.x * 64;
    int colBase = blockIdx.y * BN;
    int wrow = rowBase + wave * 32;
    int r0 = wrow + l16;
    int r0c = min(r0, M - 1), r1c = min(r0 + 16, M - 1);

    f32x4 acc[2][NT];
#pragma unroll
    for (int rf = 0; rf < 2; ++rf)
#pragma unroll
        for (int n = 0; n < NT; ++n) acc[rf][n] = (f32x4){0.f, 0.f, 0.f, 0.f};

    const short* bp[NT];
#pragma unroll
    for (int n = 0; n < NT; ++n)
        bp[n] = Bg + (size_t)(colBase + n * 16 + l16) * (2 * KPAD) + quad * 8;

    const float* af0 = nullptr;
    const float* af1 = nullptr;
    const short* a00 = nullptr;
    const short* a01 = nullptr;
    const short* a10 = nullptr;
    const short* a11 = nullptr;
    if constexpr (AFP32) {
        const float* A = (const float*)A0v;
        af0 = A + (size_t)r0c * KREAL + quad * 8;
        af1 = A + (size_t)r1c * KREAL + quad * 8;
    } else {
        const short* A0 = (const short*)A0v;
        a00 = A0 + (size_t)r0c * KS0 + quad * 8;
        a01 = A0 + (size_t)r1c * KS0 + quad * 8;
        if constexpr (W1 > 0) {
            a10 = A1 + (size_t)r0c * W1 + quad * 8;
            a11 = A1 + (size_t)r1c * W1 + quad * 8;
        }
    }

#pragma unroll
    for (int s = 0; s < NS; ++s) {
        const int k0 = s * 32;
        short8 a0, a1;
        if constexpr (AFP32) {
            int kg = k0 + quad * 8;
            f32x4 f00 = {0.f, 0.f, 0.f, 0.f}, f01 = {0.f, 0.f, 0.f, 0.f};
            f32x4 f10 = {0.f, 0.f, 0.f, 0.f}, f11 = {0.f, 0.f, 0.f, 0.f};
            if (kg < KREAL) {
                f00 = *(const f32x4*)(af0 + k0);
                f10 = *(const f32x4*)(af1 + k0);
            }
            if (kg + 4 < KREAL) {
                f01 = *(const f32x4*)(af0 + k0 + 4);
                f11 = *(const f32x4*)(af1 + k0 + 4);
            }
#pragma unroll
            for (int j = 0; j < 4; ++j) {
                a0[j] = (short)f2bf(f00[j]);
                a0[j + 4] = (short)f2bf(f01[j]);
                a1[j] = (short)f2bf(f10[j]);
                a1[j + 4] = (short)f2bf(f11[j]);
            }
        } else {
            if constexpr (W1 > 0) {
                if (k0 >= KS0) {
                    a0 = *(const short8*)(a10 + (k0 - KS0));
                    a1 = *(const short8*)(a11 + (k0 - KS0));
                } else {
                    a0 = *(const short8*)(a00 + k0);
                    a1 = *(const short8*)(a01 + k0);
                }
            } else {
                a0 = *(const short8*)(a00 + k0);
                a1 = *(const short8*)(a01 + k0);
            }
        }
#pragma unroll
        for (int n = 0; n < NT; ++n) {
            short8 bh = *(const short8*)(bp[n] + k0);
            short8 bl = *(const short8*)(bp[n] + KPAD + k0);
            acc[0][n] = __builtin_amdgcn_mfma_f32_16x16x32_bf16(a0, bh, acc[0][n], 0, 0, 0);
            acc[0][n] = __builtin_amdgcn_mfma_f32_16x16x32_bf16(a0, bl, acc[0][n], 0, 0, 0);
            acc[1][n] = __builtin_amdgcn_mfma_f32_16x16x32_bf16(a1, bh, acc[1][n], 0, 0, 0);
            acc[1][n] = __builtin_amdgcn_mfma_f32_16x16x32_bf16(a1, bl, acc[1][n], 0, 0, 0);
        }
    }

    // ---- epilogue: C-layout col=lane&15, row=quad*4+reg ----
#pragma unroll
    for (int rf = 0; rf < 2; ++rf) {
        int gr0 = wrow + rf * 16 + quad * 4;
#pragma unroll
        for (int n = 0; n < NT; ++n) {
            int gc = colBase + n * 16 + l16;
            float b = bias ? bias[gc] : 0.f;
#pragma unroll
            for (int r = 0; r < 4; ++r) {
                int gr = gr0 + r;
                if (gr < M) {
                    float v = acc[rf][n][r] + b;
                    if (RELU) v = fmaxf(v, 0.f);
                    if (CH) CH[(size_t)gr * ldc + gc] = (short)f2bf(v);
                    if (F0) {
                        if (gc < splitN) F0[(size_t)gr * splitN + gc] = v;
                        else             F1[(size_t)gr * (N - splitN) + (gc - splitN)] = v;
                    }
                }
            }
        }
    }
}

// ---------------- fused layer-3 aggregation + bias + residual + log_softmax ----------------
__global__ __launch_bounds__(256) void k_final(
    const float* __restrict__ p, const float* __restrict__ q,
    const int* __restrict__ offs, const int* __restrict__ ssrc,
    const float* __restrict__ bl3, float* __restrict__ out) {
    int wid = (blockIdx.x * 256 + threadIdx.x) >> 6;
    int lane = threadIdx.x & 63;
    if (wid >= NN) return;
    bool act = lane < NCLS;
    int beg = offs[wid], end = offs[wid + 1];
    float a0 = 0.f, a1 = 0.f;
    int i = beg;
    for (; i + 1 < end; i += 2) {
        int s0 = ssrc[i], s1 = ssrc[i + 1];
        a0 += act ? p[(size_t)s0 * NCLS + lane] : 0.f;
        a1 += act ? p[(size_t)s1 * NCLS + lane] : 0.f;
    }
    if (i < end) {
        int s0 = ssrc[i];
        a0 += act ? p[(size_t)s0 * NCLS + lane] : 0.f;
    }
    float inv = 1.f / fmaxf((float)(end - beg), 1.f);
    float v = act ? ((a0 + a1) * inv + bl3[lane] + q[(size_t)wid * NCLS + lane]) : -INFINITY;
    float m = v;
#pragma unroll
    for (int off = 32; off > 0; off >>= 1) m = fmaxf(m, __shfl_xor(m, off));
    float e = act ? expf(v - m) : 0.f;
    float s = e;
#pragma unroll
    for (int off = 32; off > 0; off >>= 1) s += __shfl_xor(s, off);
    float ls = logf(s);
    if (act) out[(size_t)wid * NCLS + lane] = v - m - ls;
}

extern "C" void kernel_launch(void* const* d_in, const int* in_sizes, int n_in,
                              void* d_out, int out_size, void* d_ws, size_t ws_size,
                              hipStream_t stream) {
    const float* x    = (const float*)d_in[0];
    const int*   ei   = (const int*)d_in[1];
    const int*   esrc = ei;        // row 0: src
    const int*   edst = ei + NE;   // row 1: dst
    const float* W_map = (const float*)d_in[2];
    const float* b_map = (const float*)d_in[3];
    const float* Wl1   = (const float*)d_in[4];
    const float* bl1   = (const float*)d_in[5];
    const float* Wr1   = (const float*)d_in[6];
    const float* Wl2   = (const float*)d_in[7];
    const float* bl2   = (const float*)d_in[8];
    const float* Wr2   = (const float*)d_in[9];
    const float* Wl3   = (const float*)d_in[10];
    const float* bl3   = (const float*)d_in[11];
    const float* Wr3   = (const float*)d_in[12];
    float* out = (float*)d_out;

    char* ws = (char*)d_ws;
    short* h0H = (short*)ws; ws += (size_t)NN * 128 * 2;
    short* m0H = (short*)ws; ws += (size_t)NN * 128 * 2;
    short* h1H = (short*)ws; ws += (size_t)NN * 128 * 2;
    short* m1H = (short*)ws; ws += (size_t)NN * 128 * 2;
    short* h2H = (short*)ws; ws += (size_t)NN * 256 * 2;
    float* p   = (float*)ws; ws += (size_t)NN * NCLS * 4;
    float* q   = (float*)ws; ws += (size_t)NN * NCLS * 4;
    short* wt  = (short*)ws; ws += (size_t)368640 * 2;
    int* deg    = (int*)ws;  ws += (size_t)NN * 4;
    int* offs   = (int*)ws;  ws += (size_t)(NN + 2) * 4;
    int* cursor = (int*)ws;  ws += (size_t)NN * 4;
    int* ssrc   = (int*)ws;  ws += (size_t)NE * 4;
    int* bsum   = (int*)ws;  ws += (size_t)256 * 4;
    int* bpre   = (int*)ws;  ws += (size_t)256 * 4;

    // interleaved hi/lo weight planes: [N][2*Kpad] (hi | lo per row)
    short* m_w  = wt + 0;       // [128][1024] (Kpad=512)
    short* b1w  = wt + 131072;  // [128][512]  = [Wr1;Wl1], Kpad=256
    short* b2w  = wt + 196608;  // [256][512]  = [Wr2;Wl2], Kpad=256
    short* b3w  = wt + 327680;  // [80][512]   = [Wl3|Wr3], Kpad=256

    // --- weight split/transpose (tiny) ---
    k_wsplit<<<(128 * 512 + 255) / 256, 256, 0, stream>>>(W_map, m_w, FIN, 128, 512, 0, 9);
    k_wsplit<<<(128 * 128 + 255) / 256, 256, 0, stream>>>(Wr1, b1w, 128, 128, 256, 0, 7);
    k_wsplit<<<(128 * 128 + 255) / 256, 256, 0, stream>>>(Wl1, b1w, 128, 128, 256, 128, 7);
    k_wsplit<<<(256 * 128 + 255) / 256, 256, 0, stream>>>(Wr2, b2w, 128, 256, 256, 0, 7);
    k_wsplit<<<(256 * 128 + 255) / 256, 256, 0, stream>>>(Wl2, b2w, 128, 256, 256, 128, 7);
    k_wsplit<<<(40 * 256 + 255) / 256, 256, 0, stream>>>(Wl3, b3w, 256, 40, 256, 0, 8);
    k_wsplit<<<(40 * 256 + 255) / 256, 256, 0, stream>>>(Wr3, b3w + 40 * 512, 256, 40, 256, 0, 8);

    // --- CSR bucketing of edges by dst (two-level scan) ---
    (void)hipMemsetAsync(deg, 0, (size_t)NN * 4, stream);
    k_count<<<(NE + 255) / 256, 256, 0, stream>>>(edst, deg);
    k_scan1<<<NB, 256, 0, stream>>>(deg, offs, bsum);
    k_scan2<<<1, 256, 0, stream>>>(bsum, bpre, offs);
    k_scan3<<<NB, 256, 0, stream>>>(offs, bpre, cursor);
    k_scatter<<<(NE + 255) / 256, 256, 0, stream>>>(esrc, edst, cursor, ssrc);

    const int g64 = (NN + 63) / 64;  // 782
    const int aggBlocks = (NN * 64) / 256;

    // h0 = x @ W_map + b_map -> h0H [NN][128] bf16
    k_mm2<128, 512, 512, FIN, true, false><<<dim3(g64, 1), 128, 0, stream>>>(
        (const void*)x, nullptr, m_w, b_map,
        h0H, 128, nullptr, nullptr, 0, NN, 128);

    // mean(h0) -> m0H
    k_aggb<<<aggBlocks, 256, 0, stream>>>(h0H, offs, ssrc, m0H);

    // h1 = relu([h0|mean] @ [Wr1;Wl1] + bl1) -> h1H
    k_mm2<128, 256, 128, 256, false, true><<<dim3(g64, 1), 128, 0, stream>>>(
        (const void*)h0H, m0H, b1w, bl1,
        h1H, 128, nullptr, nullptr, 0, NN, 128);

    // mean(h1) -> m1H
    k_aggb<<<aggBlocks, 256, 0, stream>>>(h1H, offs, ssrc, m1H);

    // h2 = relu([h1|mean] @ [Wr2;Wl2] + bl2) -> h2H [NN][256]
    k_mm2<128, 256, 128, 256, false, true><<<dim3(g64, 2), 128, 0, stream>>>(
        (const void*)h1H, m1H, b2w, bl2,
        h2H, 256, nullptr, nullptr, 0, NN, 256);

    // [p|q] = h2 @ [Wl3|Wr3]  (no bias; bl3 added in k_final)
    k_mm2<80, 256, 256, 256, false, false><<<dim3(g64, 1), 128, 0, stream>>>(
        (const void*)h2H, nullptr, b3w, nullptr,
        nullptr, 0, p, q, NCLS, NN, 80);

    // fused: logits = mean_agg(p) + bl3 + q; log_softmax -> out
    k_final<<<aggBlocks, 256, 0, stream>>>(p, q, offs, ssrc, bl3, out);
}